// Round 7
// baseline (228.504 us; speedup 1.0000x reference)
//
#include <hip/hip_runtime.h>
#include <hip/hip_cooperative_groups.h>
namespace cg = cooperative_groups;

#define NN  16384
#define NE  524288
#define D   128
#define CAP 128     // max in-degree slots; Poisson(32) tail P(>128) ~ 1e-43
#define GB  512
#define BT  256

// ws layout (bytes); ws_size evidenced ~268 MB (poison fill WRITE_SIZE), use 20.1 MB
#define OFF_CNT  0u           // int[16384]
#define OFF_SLAB 65536u       // u16[16384*128] = 4 MB (ids fit 14 bits; bit15 = keep flag)
#define OFF_Y    4259840u     // float[16384*128] = 8 MB   y = x @ W^T
#define OFF_Z    12648448u    // float[16384*128] = 8 MB   z = x @ B^T

typedef __bf16 bf16x4 __attribute__((ext_vector_type(4)));
typedef __bf16 bf16x8 __attribute__((ext_vector_type(8)));
typedef float  f32x4  __attribute__((ext_vector_type(4)));
typedef unsigned short u16;

// phases: bit0 = P1 (zero cnt + GEMM yz), bit1 = P2 (fill), bit2 = P3 (gather).
// coop: 1 => grid.sync() between phases (cooperative launch); 0 => phases split
// across separate launches (stream order provides the barriers).
__global__ __launch_bounds__(BT, 2) void fused_k(const float* __restrict__ x,
                                                 const int* __restrict__ ei,
                                                 const float* __restrict__ W,
                                                 const float* __restrict__ Bm,
                                                 float* __restrict__ out,
                                                 char* __restrict__ ws,
                                                 int phases, int coop) {
  __shared__ __align__(16) char smem[23040];   // P1: sA 2.5K + sB 20K; P3: s_col 4K
  __shared__ int s_any;
  int b = blockIdx.x, t = threadIdx.x;
  int* cnt  = (int*)(ws + OFF_CNT);
  u16* slab = (u16*)(ws + OFF_SLAB);

  if (phases & 1) {
    // zero cnt: 4096 int4 over 512 blocks = 8 per block
    if (t < 8) ((int4*)cnt)[b * 8 + t] = int4{0, 0, 0, 0};

    // GEMM: rows [32b,32b+32) of [y|z] = x @ [W|B]^T, bf16 MFMA, K=128.
    float* y = (float*)(ws + OFF_Y);
    float* z = (float*)(ws + OFF_Z);
    __bf16 (*sA)[40] = (__bf16(*)[40])smem;            // [32][40]
    __bf16 (*sB)[40] = (__bf16(*)[40])(smem + 2560);   // [256][40]
    int l = t & 63, wid = t >> 6;
    int g = l >> 4, ln = l & 15;
    int mh = wid & 1, nh = wid >> 1;   // wave -> (16-row half, 128-col half)
    int row0 = b * 32;
    f32x4 acc[8];
#pragma unroll
    for (int nb = 0; nb < 8; ++nb) acc[nb] = f32x4{0.f, 0.f, 0.f, 0.f};

    for (int kc = 0; kc < 4; ++kc) {
      int kb = kc * 32;
      __syncthreads();
      {                                   // A: 32 rows x 32 k from x
        int rr = t >> 3, q = t & 7;
        float4 v = *(const float4*)&x[(size_t)(row0 + rr) * D + kb + q * 4];
        bf16x4 w = {(__bf16)v.x, (__bf16)v.y, (__bf16)v.z, (__bf16)v.w};
        *(bf16x4*)&sA[rr][q * 4] = w;
      }
#pragma unroll
      for (int u = 0; u < 8; ++u) {       // B': 256 rows (W;B) x 32 k
        int f = u * 256 + t;
        int rr = f >> 3, q = f & 7;
        const float* Bp = (rr < 128) ? &W[(size_t)rr * D] : &Bm[(size_t)(rr - 128) * D];
        float4 v = *(const float4*)&Bp[kb + q * 4];
        bf16x4 w = {(__bf16)v.x, (__bf16)v.y, (__bf16)v.z, (__bf16)v.w};
        *(bf16x4*)&sB[rr][q * 4] = w;
      }
      __syncthreads();
      bf16x8 afr = *(const bf16x8*)&sA[mh * 16 + ln][g * 8];
#pragma unroll
      for (int nb = 0; nb < 8; ++nb) {
        bf16x8 bfr = *(const bf16x8*)&sB[nh * 128 + nb * 16 + ln][g * 8];
        acc[nb] = __builtin_amdgcn_mfma_f32_16x16x32_bf16(afr, bfr, acc[nb], 0, 0, 0);
      }
    }
    // C/D: col = ln, row = g*4+i [verified r4-r6]; nh=0 -> y, nh=1 -> z
#pragma unroll
    for (int nb = 0; nb < 8; ++nb)
#pragma unroll
      for (int i = 0; i < 4; ++i) {
        int row = row0 + mh * 16 + g * 4 + i;
        int c = nb * 16 + ln;
        if (nh == 0) y[(size_t)row * D + c] = acc[nb][i];
        else         z[(size_t)row * D + c] = acc[nb][i];
      }
  }

  if (coop) cg::this_grid().sync();

  if (phases & 2) {
    // per-block format detect over own slice: int64 => odd words all zero
    if (t == 0) s_any = 0;
    __syncthreads();
    int base = b * 1024;
    int any = 0;
#pragma unroll
    for (int u = 0; u < 4; ++u) any |= ei[2 * (base + u * 256 + t) + 1];
    if (any) atomicOr(&s_any, 1);
    __syncthreads();
    int is32 = s_any;
#pragma unroll
    for (int u = 0; u < 4; ++u) {
      int i = base + u * 256 + t;
      int s = is32 ? ei[i] : ei[2 * i];
      int d = is32 ? ei[NE + i] : ei[2 * (NE + i)];
      int slot = atomicAdd(&cnt[d], 1);
      if (slot < CAP) slab[((size_t)d << 7) + slot] = (u16)s;
    }
  }

  if (coop) cg::this_grid().sync();

  if (phases & 4) {
    // out[row] = dinv * sum_{unique src} y[src] + z[row]
    u16 (*s_col)[CAP] = (u16(*)[CAP])smem;   // [16][128]
    const float* y = (const float*)(ws + OFF_Y);
    const float* z = (const float*)(ws + OFF_Z);
    int lane = t & 15, r = t >> 4;
    for (int pass = 0; pass < 2; ++pass) {
      int row = (pass * GB + b) * 16 + r;
      int k = cnt[row];
      if (k > CAP) k = CAP;
      const u16* srow = slab + ((size_t)row << 7);
      for (int j = lane; j < k; j += 16) s_col[r][j] = srow[j];

      int lu = 0;
      for (int j = lane; j < k; j += 16) {
        int c = s_col[r][j] & 0x3FFF;
        bool kp = true;
        for (int j2 = 0; j2 < j; ++j2)
          if ((s_col[r][j2] & 0x3FFF) == c) { kp = false; break; }
        if (kp) { s_col[r][j] = (u16)(c | 0x8000); lu++; }
      }
#pragma unroll
      for (int off = 8; off; off >>= 1) lu += __shfl_xor(lu, off);
      float dinv = 1.0f / (float)(lu > 0 ? lu : 1);

      float acc[8] = {0, 0, 0, 0, 0, 0, 0, 0};
      const float* yl = y + lane * 8;
#define ACC8(pa, pb, ff)                                                  \
      { float4 va = *(const float4*)(pa), vb = *(const float4*)(pb);      \
        acc[0] += ff * va.x; acc[1] += ff * va.y;                         \
        acc[2] += ff * va.z; acc[3] += ff * va.w;                         \
        acc[4] += ff * vb.x; acc[5] += ff * vb.y;                         \
        acc[6] += ff * vb.z; acc[7] += ff * vb.w; }
      int j = 0;
      for (; j + 2 <= k; j += 2) {
        int c0 = s_col[r][j], c1 = s_col[r][j + 1];
        float f0 = (c0 >> 15) ? 1.0f : 0.0f, f1 = (c1 >> 15) ? 1.0f : 0.0f;
        const float* p0 = yl + (size_t)(c0 & 0x3FFF) * D;
        const float* p1 = yl + (size_t)(c1 & 0x3FFF) * D;
        ACC8(p0, p0 + 4, f0)
        ACC8(p1, p1 + 4, f1)
      }
      if (j < k) {
        int c0 = s_col[r][j];
        float f0 = (c0 >> 15) ? 1.0f : 0.0f;
        const float* p0 = yl + (size_t)(c0 & 0x3FFF) * D;
        ACC8(p0, p0 + 4, f0)
      }
#undef ACC8
      const float* zr = z + (size_t)row * D + lane * 8;
      float4 z0 = *(const float4*)zr, z1 = *(const float4*)(zr + 4);
      float4 o0 = {acc[0] * dinv + z0.x, acc[1] * dinv + z0.y,
                   acc[2] * dinv + z0.z, acc[3] * dinv + z0.w};
      float4 o1 = {acc[4] * dinv + z1.x, acc[5] * dinv + z1.y,
                   acc[6] * dinv + z1.z, acc[7] * dinv + z1.w};
      float* dst = out + (size_t)row * D + lane * 8;
      *(float4*)dst = o0;
      *(float4*)(dst + 4) = o1;
    }
  }
}

extern "C" void kernel_launch(void* const* d_in, const int* in_sizes, int n_in,
                              void* d_out, int out_size, void* d_ws, size_t ws_size,
                              hipStream_t stream) {
  const float* x = (const float*)d_in[0];
  const int* ei = (const int*)d_in[1];
  const float* W = (const float*)d_in[2];
  const float* Bm = (const float*)d_in[3];
  float* out = (float*)d_out;
  char* ws = (char*)d_ws;

  int phases = 7, coop = 1;
  void* args[] = {(void*)&x, (void*)&ei, (void*)&W, (void*)&Bm,
                  (void*)&out, (void*)&ws, (void*)&phases, (void*)&coop};
  hipError_t e = hipLaunchCooperativeKernel((void*)fused_k, dim3(GB), dim3(BT),
                                            args, 0, stream);
  if (e != hipSuccess) {
    // fallback: same kernel, phases split across launches (stream = barrier)
    fused_k<<<GB, BT, 0, stream>>>(x, ei, W, Bm, out, ws, 1, 0);
    fused_k<<<GB, BT, 0, stream>>>(x, ei, W, Bm, out, ws, 2, 0);
    fused_k<<<GB, BT, 0, stream>>>(x, ei, W, Bm, out, ws, 4, 0);
  }
}

// Round 8
// 77.366 us; speedup vs baseline: 2.9536x; 2.9536x over previous
//
#include <hip/hip_runtime.h>

#define NN  16384
#define NE  524288
#define D   128
#define CAP 128     // max in-degree slots; Poisson(32) tail P(>128) ~ 1e-43

// ws layout (bytes); total 20.6 MB (ws evidenced ~268 MB)
#define OFF_CNT  0u           // int[16384]
#define OFF_SLAB 65536u       // u16[16384*128] = 4 MB (ids fit 14 bits; bit15 = keep)
#define OFF_Y    4259840u     // float[16384*128] = 8 MB   y = x @ W^T
#define OFF_Z    12648448u    // float[16384*128] = 8 MB   z = x @ B^T

typedef __bf16 bf16x4 __attribute__((ext_vector_type(4)));
typedef __bf16 bf16x8 __attribute__((ext_vector_type(8)));
typedef float  f32x4  __attribute__((ext_vector_type(4)));
typedef unsigned short u16;

// L1: zero cnt (side job) + [y|z] = x @ [W|B]^T via bf16 MFMA, K=128.
// 512 blocks x 32 rows; 4 waves -> (row-half, col-half) quadrants.
__global__ __launch_bounds__(256, 2) void gemm_yz_k(const float* __restrict__ x,
                                                    const float* __restrict__ W,
                                                    const float* __restrict__ Bm,
                                                    float* __restrict__ y,
                                                    float* __restrict__ z,
                                                    int* __restrict__ cnt) {
  __shared__ __bf16 sA[32][40];    // 2.5 KB
  __shared__ __bf16 sB[256][40];   // 20 KB  (rows 0..127 = W, 128..255 = B)
  int b = blockIdx.x, t = threadIdx.x;
  if (t < 8) ((int4*)cnt)[b * 8 + t] = int4{0, 0, 0, 0};   // 512*8 = 4096 int4

  int l = t & 63, wid = t >> 6;
  int g = l >> 4, ln = l & 15;
  int mh = wid & 1, nh = wid >> 1;
  int row0 = b * 32;
  f32x4 acc[8];
#pragma unroll
  for (int nb = 0; nb < 8; ++nb) acc[nb] = f32x4{0.f, 0.f, 0.f, 0.f};

  for (int kc = 0; kc < 4; ++kc) {
    int kb = kc * 32;
    __syncthreads();
    {                                   // A: 32 rows x 32 k from x
      int rr = t >> 3, q = t & 7;
      float4 v = *(const float4*)&x[(size_t)(row0 + rr) * D + kb + q * 4];
      bf16x4 w = {(__bf16)v.x, (__bf16)v.y, (__bf16)v.z, (__bf16)v.w};
      *(bf16x4*)&sA[rr][q * 4] = w;
    }
#pragma unroll
    for (int u = 0; u < 8; ++u) {       // B': 256 rows (W;B) x 32 k
      int f = u * 256 + t;
      int rr = f >> 3, q = f & 7;
      const float* Bp = (rr < 128) ? &W[(size_t)rr * D] : &Bm[(size_t)(rr - 128) * D];
      float4 v = *(const float4*)&Bp[kb + q * 4];
      bf16x4 w = {(__bf16)v.x, (__bf16)v.y, (__bf16)v.z, (__bf16)v.w};
      *(bf16x4*)&sB[rr][q * 4] = w;
    }
    __syncthreads();
    bf16x8 afr = *(const bf16x8*)&sA[mh * 16 + ln][g * 8];
#pragma unroll
    for (int nb = 0; nb < 8; ++nb) {
      bf16x8 bfr = *(const bf16x8*)&sB[nh * 128 + nb * 16 + ln][g * 8];
      acc[nb] = __builtin_amdgcn_mfma_f32_16x16x32_bf16(afr, bfr, acc[nb], 0, 0, 0);
    }
  }
  // C/D: col = ln, row = g*4+i [verified r4-r7]; nh=0 -> y, nh=1 -> z
  float* dstm = (nh == 0) ? y : z;
#pragma unroll
  for (int nb = 0; nb < 8; ++nb)
#pragma unroll
    for (int i = 0; i < 4; ++i)
      dstm[(size_t)(row0 + mh * 16 + g * 4 + i) * D + nb * 16 + ln] = acc[nb][i];
}

// L2: per-block edge-width detect + slab fill. 512 blocks x 1024 edges.
// int64 edges => odd int32 words (high words) all zero over the slice.
__global__ __launch_bounds__(256) void fill_k(const int* __restrict__ ei,
                                              int* __restrict__ cnt,
                                              u16* __restrict__ slab) {
  __shared__ int s_any;
  int b = blockIdx.x, t = threadIdx.x;
  if (t == 0) s_any = 0;
  __syncthreads();
  int base = b * 1024;
  int any = 0;
#pragma unroll
  for (int u = 0; u < 4; ++u) any |= ei[2 * (base + u * 256 + t) + 1];
  if (any) atomicOr(&s_any, 1);
  __syncthreads();
  int is32 = s_any;
#pragma unroll
  for (int u = 0; u < 4; ++u) {
    int i = base + u * 256 + t;
    int s = is32 ? ei[i] : ei[2 * i];
    int d = is32 ? ei[NE + i] : ei[2 * (NE + i)];
    int slot = atomicAdd(&cnt[d], 1);
    if (slot < CAP) slab[((size_t)d << 7) + slot] = (u16)s;
  }
}

// L3: out[row] = dinv * sum_{unique src} y[src] + z[row].
// One row per 32-lane group (fp32 row = 32 lanes x float4); LDS intra-wave.
#define RPB 8
__global__ __launch_bounds__(256) void gather_k(const int* __restrict__ cnt,
                                                const u16* __restrict__ slab,
                                                const float* __restrict__ y,
                                                const float* __restrict__ z,
                                                float* __restrict__ out) {
  __shared__ u16 s_col[RPB][CAP];   // 2 KB
  int t = threadIdx.x, lane = t & 31, r = t >> 5;
  int row = blockIdx.x * RPB + r;
  int k = cnt[row];
  if (k > CAP) k = CAP;
  const u16* srow = slab + ((size_t)row << 7);
  for (int j = lane; j < k; j += 32) s_col[r][j] = srow[j];

  int lu = 0;
  for (int j = lane; j < k; j += 32) {
    int c = s_col[r][j] & 0x3FFF;
    bool kp = true;
    for (int j2 = 0; j2 < j; ++j2)
      if ((s_col[r][j2] & 0x3FFF) == c) { kp = false; break; }  // mask: race-safe
    if (kp) { s_col[r][j] = (u16)(c | 0x8000); lu++; }
  }
#pragma unroll
  for (int off = 16; off; off >>= 1) lu += __shfl_xor(lu, off);
  float dinv = 1.0f / (float)(lu > 0 ? lu : 1);

  float4 a0 = {0,0,0,0}, a1 = {0,0,0,0}, a2 = {0,0,0,0}, a3 = {0,0,0,0};
  const float* yl = y + lane * 4;
#define FMA4(aa, vv, ff) { aa.x += ff*vv.x; aa.y += ff*vv.y; aa.z += ff*vv.z; aa.w += ff*vv.w; }
  int j = 0;
  for (; j + 4 <= k; j += 4) {
    int c0 = s_col[r][j], c1 = s_col[r][j+1], c2 = s_col[r][j+2], c3 = s_col[r][j+3];
    float f0 = (c0 >> 15) ? 1.0f : 0.0f, f1 = (c1 >> 15) ? 1.0f : 0.0f;
    float f2 = (c2 >> 15) ? 1.0f : 0.0f, f3 = (c3 >> 15) ? 1.0f : 0.0f;
    float4 v0 = *(const float4*)(yl + (size_t)(c0 & 0x3FFF) * D);
    float4 v1 = *(const float4*)(yl + (size_t)(c1 & 0x3FFF) * D);
    float4 v2 = *(const float4*)(yl + (size_t)(c2 & 0x3FFF) * D);
    float4 v3 = *(const float4*)(yl + (size_t)(c3 & 0x3FFF) * D);
    FMA4(a0, v0, f0) FMA4(a1, v1, f1) FMA4(a2, v2, f2) FMA4(a3, v3, f3)
  }
  for (; j < k; ++j) {
    int c0 = s_col[r][j];
    float f0 = (c0 >> 15) ? 1.0f : 0.0f;
    float4 v0 = *(const float4*)(yl + (size_t)(c0 & 0x3FFF) * D);
    FMA4(a0, v0, f0)
  }
#undef FMA4
  float4 zv = *(const float4*)(z + (size_t)row * D + lane * 4);
  float4 o;
  o.x = (a0.x + a1.x + a2.x + a3.x) * dinv + zv.x;
  o.y = (a0.y + a1.y + a2.y + a3.y) * dinv + zv.y;
  o.z = (a0.z + a1.z + a2.z + a3.z) * dinv + zv.z;
  o.w = (a0.w + a1.w + a2.w + a3.w) * dinv + zv.w;
  *(float4*)(out + (size_t)row * D + lane * 4) = o;
}

extern "C" void kernel_launch(void* const* d_in, const int* in_sizes, int n_in,
                              void* d_out, int out_size, void* d_ws, size_t ws_size,
                              hipStream_t stream) {
  const float* x = (const float*)d_in[0];
  const int* ei = (const int*)d_in[1];
  const float* W = (const float*)d_in[2];
  const float* Bm = (const float*)d_in[3];
  float* out = (float*)d_out;
  char* ws = (char*)d_ws;
  int* cnt = (int*)(ws + OFF_CNT);
  u16* slab = (u16*)(ws + OFF_SLAB);
  float* y = (float*)(ws + OFF_Y);
  float* z = (float*)(ws + OFF_Z);

  gemm_yz_k<<<512, 256, 0, stream>>>(x, W, Bm, y, z, cnt);
  fill_k<<<512, 256, 0, stream>>>(ei, cnt, slab);
  gather_k<<<NN / RPB, 256, 0, stream>>>(cnt, slab, y, z, out);
}

// Round 9
// 76.979 us; speedup vs baseline: 2.9684x; 1.0050x over previous
//
#include <hip/hip_runtime.h>

#define NN  16384
#define NE  524288
#define D   128
#define CAP 128     // max in-degree slots; Poisson(32) tail P(>128) ~ 1e-43

// ws layout (bytes); total 20.6 MB (ws evidenced ~268 MB)
#define OFF_CNT  0u           // int[16384]
#define OFF_SLAB 65536u       // u16[16384*128] = 4 MB (ids fit 14 bits)
#define OFF_Y    4259840u     // float[16384*128] = 8 MB   y = x @ W^T
#define OFF_Z    12648448u    // float[16384*128] = 8 MB   z = x @ B^T

typedef __bf16 bf16x4 __attribute__((ext_vector_type(4)));
typedef __bf16 bf16x8 __attribute__((ext_vector_type(8)));
typedef float  f32x4  __attribute__((ext_vector_type(4)));
typedef unsigned short u16;

// L1: zero cnt (side job) + [y|z] = x @ [W|B]^T via bf16 MFMA, K=128.
__global__ __launch_bounds__(256, 2) void gemm_yz_k(const float* __restrict__ x,
                                                    const float* __restrict__ W,
                                                    const float* __restrict__ Bm,
                                                    float* __restrict__ y,
                                                    float* __restrict__ z,
                                                    int* __restrict__ cnt) {
  __shared__ __bf16 sA[32][40];    // 2.5 KB
  __shared__ __bf16 sB[256][40];   // 20 KB  (rows 0..127 = W, 128..255 = B)
  int b = blockIdx.x, t = threadIdx.x;
  if (t < 8) ((int4*)cnt)[b * 8 + t] = int4{0, 0, 0, 0};

  int l = t & 63, wid = t >> 6;
  int g = l >> 4, ln = l & 15;
  int mh = wid & 1, nh = wid >> 1;
  int row0 = b * 32;
  f32x4 acc[8];
#pragma unroll
  for (int nb = 0; nb < 8; ++nb) acc[nb] = f32x4{0.f, 0.f, 0.f, 0.f};

  for (int kc = 0; kc < 4; ++kc) {
    int kb = kc * 32;
    __syncthreads();
    {                                   // A: 32 rows x 32 k from x
      int rr = t >> 3, q = t & 7;
      float4 v = *(const float4*)&x[(size_t)(row0 + rr) * D + kb + q * 4];
      bf16x4 w = {(__bf16)v.x, (__bf16)v.y, (__bf16)v.z, (__bf16)v.w};
      *(bf16x4*)&sA[rr][q * 4] = w;
    }
#pragma unroll
    for (int u = 0; u < 8; ++u) {       // B': 256 rows (W;B) x 32 k
      int f = u * 256 + t;
      int rr = f >> 3, q = f & 7;
      const float* Bp = (rr < 128) ? &W[(size_t)rr * D] : &Bm[(size_t)(rr - 128) * D];
      float4 v = *(const float4*)&Bp[kb + q * 4];
      bf16x4 w = {(__bf16)v.x, (__bf16)v.y, (__bf16)v.z, (__bf16)v.w};
      *(bf16x4*)&sB[rr][q * 4] = w;
    }
    __syncthreads();
    bf16x8 afr = *(const bf16x8*)&sA[mh * 16 + ln][g * 8];
#pragma unroll
    for (int nb = 0; nb < 8; ++nb) {
      bf16x8 bfr = *(const bf16x8*)&sB[nh * 128 + nb * 16 + ln][g * 8];
      acc[nb] = __builtin_amdgcn_mfma_f32_16x16x32_bf16(afr, bfr, acc[nb], 0, 0, 0);
    }
  }
  float* dstm = (nh == 0) ? y : z;   // C/D: col = ln, row = g*4+i [verified r4-r7]
#pragma unroll
  for (int nb = 0; nb < 8; ++nb)
#pragma unroll
    for (int i = 0; i < 4; ++i)
      dstm[(size_t)(row0 + mh * 16 + g * 4 + i) * D + nb * 16 + ln] = acc[nb][i];
}

// L2: per-block edge-width detect + slab fill. 512 blocks x 1024 edges.
__global__ __launch_bounds__(256) void fill_k(const int* __restrict__ ei,
                                              int* __restrict__ cnt,
                                              u16* __restrict__ slab) {
  __shared__ int s_any;
  int b = blockIdx.x, t = threadIdx.x;
  if (t == 0) s_any = 0;
  __syncthreads();
  int base = b * 1024;
  int any = 0;
#pragma unroll
  for (int u = 0; u < 4; ++u) any |= ei[2 * (base + u * 256 + t) + 1];
  if (any) atomicOr(&s_any, 1);
  __syncthreads();
  int is32 = s_any;
#pragma unroll
  for (int u = 0; u < 4; ++u) {
    int i = base + u * 256 + t;
    int s = is32 ? ei[i] : ei[2 * i];
    int d = is32 ? ei[NE + i] : ei[2 * (NE + i)];
    int slot = atomicAdd(&cnt[d], 1);
    if (slot < CAP) slab[((size_t)d << 7) + slot] = (u16)s;
  }
}

// L3: out[row] = dinv * sum_{unique src} y[src] + z[row].
// One row per 32-lane group. Dedup via per-row LDS bitmap (16384 bits):
// one parallel atomicOr round, O(k/32) dependent steps (was O(k) serial
// LDS-latency chain — the r1-r8 latency bottleneck theory under test).
#define RPB 8
__global__ __launch_bounds__(256) void gather_k(const int* __restrict__ cnt,
                                                const u16* __restrict__ slab,
                                                const float* __restrict__ y,
                                                const float* __restrict__ z,
                                                float* __restrict__ out) {
  __shared__ u16 s_col[RPB][CAP];        // 2 KB
  __shared__ unsigned s_bm[RPB][512];    // 16 KB: 16384-bit bitmap per row
  int t = threadIdx.x, lane = t & 31, r = t >> 5;
  int row = blockIdx.x * RPB + r;
  int k = cnt[row];
  if (k > CAP) k = CAP;
  const u16* srow = slab + ((size_t)row << 7);

#pragma unroll
  for (int u = 0; u < 16; ++u) s_bm[r][u * 32 + lane] = 0u;   // zero bitmap
  for (int j = lane; j < k; j += 32) s_col[r][j] = srow[j];

  int lu = 0;
  for (int j = lane; j < k; j += 32) {
    unsigned c = s_col[r][j];
    unsigned bit = 1u << (c & 31);
    unsigned old = atomicOr(&s_bm[r][c >> 5], bit);
    int kp = (old & bit) ? 0 : 1;
    s_col[r][j] = (u16)(c | (kp << 15));
    lu += kp;
  }
#pragma unroll
  for (int off = 16; off; off >>= 1) lu += __shfl_xor(lu, off);
  float dinv = 1.0f / (float)(lu > 0 ? lu : 1);

  float4 a[8];
#pragma unroll
  for (int u = 0; u < 8; ++u) a[u] = float4{0.f, 0.f, 0.f, 0.f};
  const float* yl = y + lane * 4;
#define FMA4(aa, vv, ff) { aa.x += ff*vv.x; aa.y += ff*vv.y; aa.z += ff*vv.z; aa.w += ff*vv.w; }
  int j = 0;
  for (; j + 8 <= k; j += 8) {
    int   c[8];
    float f[8];
    float4 v[8];
#pragma unroll
    for (int u = 0; u < 8; ++u) {
      c[u] = s_col[r][j + u];
      f[u] = (c[u] >> 15) ? 1.0f : 0.0f;
      v[u] = *(const float4*)(yl + (size_t)(c[u] & 0x3FFF) * D);
    }
#pragma unroll
    for (int u = 0; u < 8; ++u) FMA4(a[u], v[u], f[u])
  }
  for (; j < k; ++j) {
    int c0 = s_col[r][j];
    float f0 = (c0 >> 15) ? 1.0f : 0.0f;
    float4 v0 = *(const float4*)(yl + (size_t)(c0 & 0x3FFF) * D);
    FMA4(a[0], v0, f0)
  }
#undef FMA4
#pragma unroll
  for (int u = 4; u < 8; ++u) {
    a[u - 4].x += a[u].x; a[u - 4].y += a[u].y;
    a[u - 4].z += a[u].z; a[u - 4].w += a[u].w;
  }
  float4 zv = *(const float4*)(z + (size_t)row * D + lane * 4);
  float4 o;
  o.x = (a[0].x + a[2].x) * dinv + zv.x;
  o.y = (a[0].y + a[2].y) * dinv + zv.y;
  o.z = (a[0].z + a[2].z) * dinv + zv.z;
  o.w = (a[0].w + a[2].w) * dinv + zv.w;
  // fold remaining pair (a1,a3)
  o.x += (a[1].x + a[3].x) * dinv;
  o.y += (a[1].y + a[3].y) * dinv;
  o.z += (a[1].z + a[3].z) * dinv;
  o.w += (a[1].w + a[3].w) * dinv;
  *(float4*)(out + (size_t)row * D + lane * 4) = o;
}

extern "C" void kernel_launch(void* const* d_in, const int* in_sizes, int n_in,
                              void* d_out, int out_size, void* d_ws, size_t ws_size,
                              hipStream_t stream) {
  const float* x = (const float*)d_in[0];
  const int* ei = (const int*)d_in[1];
  const float* W = (const float*)d_in[2];
  const float* Bm = (const float*)d_in[3];
  float* out = (float*)d_out;
  char* ws = (char*)d_ws;
  int* cnt = (int*)(ws + OFF_CNT);
  u16* slab = (u16*)(ws + OFF_SLAB);
  float* y = (float*)(ws + OFF_Y);
  float* z = (float*)(ws + OFF_Z);

  gemm_yz_k<<<512, 256, 0, stream>>>(x, W, Bm, y, z, cnt);
  fill_k<<<512, 256, 0, stream>>>(ei, cnt, slab);
  gather_k<<<NN / RPB, 256, 0, stream>>>(cnt, slab, y, z, out);
}

// Round 11
// 70.636 us; speedup vs baseline: 3.2350x; 1.0898x over previous
//
#include <hip/hip_runtime.h>

#define NN  16384
#define NE  524288
#define D   128
#define GEMMB 512
#define FILLB 256

// ws layout (bytes); total 48 MB (ws evidenced ~260 MB)
#define OFF_BM 0u          // uint[16384*512] = 32 MB adjacency bitmap: bit(dst,src)
#define OFF_Y  33554432u   // float[16384*128] = 8 MB   y = x @ W^T
#define OFF_Z  41943040u   // float[16384*128] = 8 MB   z = x @ B^T
#define BM_BYTES 33554432u // NN * 512 words * 4 B  (r10 bug: was NN*64 = 1 MB)

typedef __bf16 bf16x4 __attribute__((ext_vector_type(4)));
typedef __bf16 bf16x8 __attribute__((ext_vector_type(8)));
typedef float  f32x4  __attribute__((ext_vector_type(4)));
typedef unsigned short u16;

// K1: blocks [0,512): [y|z] = x @ [W|B]^T via bf16 MFMA (K=128, 32 rows/block).
//     blocks [512,768): edge pass -> adjacency bitmap atomicOr (2048 edges/block).
// Data-independent roles fused so MFMA-bound and atomic-bound work co-schedule.
__global__ __launch_bounds__(256, 2) void k1(const float* __restrict__ x,
                                             const int* __restrict__ ei,
                                             const float* __restrict__ W,
                                             const float* __restrict__ Bm,
                                             float* __restrict__ y,
                                             float* __restrict__ z,
                                             unsigned* __restrict__ bm) {
  __shared__ __bf16 sA[32][40];    // 2.5 KB
  __shared__ __bf16 sB[256][40];   // 20 KB  (rows 0..127 = W, 128..255 = B)
  __shared__ int s_any;
  int b = blockIdx.x, t = threadIdx.x;

  if (b < GEMMB) {
    int l = t & 63, wid = t >> 6;
    int g = l >> 4, ln = l & 15;
    int mh = wid & 1, nh = wid >> 1;
    int row0 = b * 32;
    f32x4 acc[8];
#pragma unroll
    for (int nb = 0; nb < 8; ++nb) acc[nb] = f32x4{0.f, 0.f, 0.f, 0.f};

    for (int kc = 0; kc < 4; ++kc) {
      int kb = kc * 32;
      __syncthreads();
      {                                   // A: 32 rows x 32 k from x
        int rr = t >> 3, q = t & 7;
        float4 v = *(const float4*)&x[(size_t)(row0 + rr) * D + kb + q * 4];
        bf16x4 w = {(__bf16)v.x, (__bf16)v.y, (__bf16)v.z, (__bf16)v.w};
        *(bf16x4*)&sA[rr][q * 4] = w;
      }
#pragma unroll
      for (int u = 0; u < 8; ++u) {       // B': 256 rows (W;B) x 32 k
        int f = u * 256 + t;
        int rr = f >> 3, q = f & 7;
        const float* Bp = (rr < 128) ? &W[(size_t)rr * D] : &Bm[(size_t)(rr - 128) * D];
        float4 v = *(const float4*)&Bp[kb + q * 4];
        bf16x4 w = {(__bf16)v.x, (__bf16)v.y, (__bf16)v.z, (__bf16)v.w};
        *(bf16x4*)&sB[rr][q * 4] = w;
      }
      __syncthreads();
      bf16x8 afr = *(const bf16x8*)&sA[mh * 16 + ln][g * 8];
#pragma unroll
      for (int nb = 0; nb < 8; ++nb) {
        bf16x8 bfr = *(const bf16x8*)&sB[nh * 128 + nb * 16 + ln][g * 8];
        acc[nb] = __builtin_amdgcn_mfma_f32_16x16x32_bf16(afr, bfr, acc[nb], 0, 0, 0);
      }
    }
    float* dstm = (nh == 0) ? y : z;   // C/D: col = ln, row = g*4+i [verified r4-r9]
#pragma unroll
    for (int nb = 0; nb < 8; ++nb)
#pragma unroll
      for (int i = 0; i < 4; ++i)
        dstm[(size_t)(row0 + mh * 16 + g * 4 + i) * D + nb * 16 + ln] = acc[nb][i];
  } else {
    // edge pass: per-block width detect (int64 => odd int32 words all zero)
    if (t == 0) s_any = 0;
    __syncthreads();
    int base = (b - GEMMB) * 2048;
    int any = 0;
#pragma unroll
    for (int u = 0; u < 8; ++u) any |= ei[2 * (base + u * 256 + t) + 1];
    if (any) atomicOr(&s_any, 1);
    __syncthreads();
    int is32 = s_any;
#pragma unroll
    for (int u = 0; u < 8; ++u) {
      int i = base + u * 256 + t;
      int s = is32 ? ei[i] : ei[2 * i];
      int d = is32 ? ei[NE + i] : ei[2 * (NE + i)];
      atomicOr(&bm[((size_t)d << 9) + (s >> 5)], 1u << (s & 31));
    }
  }
}

// K2: out[row] = (1/max(deg,1)) * sum_{src: bit set} y[src] + z[row].
// One row per 32-lane group. Neighbor list rebuilt from the bitmap row with a
// deterministic prefix-scan compaction (ascending src order, replay-stable).
#define RPB 8
__global__ __launch_bounds__(256) void gather_k(const unsigned* __restrict__ bm,
                                                const float* __restrict__ y,
                                                const float* __restrict__ z,
                                                float* __restrict__ out) {
  __shared__ u16 s_col[RPB][128];   // 2 KB
  int t = threadIdx.x, lane = t & 31, r = t >> 5;
  int row = blockIdx.x * RPB + r;
  const unsigned* bmr = bm + ((size_t)row << 9);

  int base = 0;
  for (int ch = 0; ch < 16; ++ch) {        // 16 chunks x 32 words = 512 words
    int w = ch * 32 + lane;
    unsigned m = bmr[w];
    int c = __popc(m);
    int inc = c;                            // inclusive scan over 32-lane group
#pragma unroll
    for (int dlt = 1; dlt < 32; dlt <<= 1) {
      int n = __shfl_up(inc, dlt, 32);
      if (lane >= dlt) inc += n;
    }
    int p = base + inc - c;                 // exclusive offset
    while (m) {
      int bpos = __ffs(m) - 1;
      m &= m - 1;
      if (p < 128) s_col[r][p] = (u16)(w * 32 + bpos);
      ++p;
    }
    base += __shfl(inc, 31, 32);            // chunk total
  }
  int deg = base;
  int k = deg > 128 ? 128 : deg;
  float dinv = 1.0f / (float)(deg > 0 ? deg : 1);

  float4 a[8];
#pragma unroll
  for (int u = 0; u < 8; ++u) a[u] = float4{0.f, 0.f, 0.f, 0.f};
  const float* yl = y + lane * 4;
#define FMA4(aa, vv) { aa.x += vv.x; aa.y += vv.y; aa.z += vv.z; aa.w += vv.w; }
  int j = 0;
  for (; j + 8 <= k; j += 8) {
    float4 v[8];
#pragma unroll
    for (int u = 0; u < 8; ++u)
      v[u] = *(const float4*)(yl + (size_t)s_col[r][j + u] * D);
#pragma unroll
    for (int u = 0; u < 8; ++u) FMA4(a[u], v[u])
  }
  for (; j < k; ++j) {
    float4 v0 = *(const float4*)(yl + (size_t)s_col[r][j] * D);
    FMA4(a[0], v0)
  }
#undef FMA4
#pragma unroll
  for (int u = 4; u < 8; ++u) {
    a[u - 4].x += a[u].x; a[u - 4].y += a[u].y;
    a[u - 4].z += a[u].z; a[u - 4].w += a[u].w;
  }
  float4 zv = *(const float4*)(z + (size_t)row * D + lane * 4);
  float4 o;
  o.x = (a[0].x + a[1].x + a[2].x + a[3].x) * dinv + zv.x;
  o.y = (a[0].y + a[1].y + a[2].y + a[3].y) * dinv + zv.y;
  o.z = (a[0].z + a[1].z + a[2].z + a[3].z) * dinv + zv.z;
  o.w = (a[0].w + a[1].w + a[2].w + a[3].w) * dinv + zv.w;
  *(float4*)(out + (size_t)row * D + lane * 4) = o;
}

extern "C" void kernel_launch(void* const* d_in, const int* in_sizes, int n_in,
                              void* d_out, int out_size, void* d_ws, size_t ws_size,
                              hipStream_t stream) {
  const float* x = (const float*)d_in[0];
  const int* ei = (const int*)d_in[1];
  const float* W = (const float*)d_in[2];
  const float* Bm = (const float*)d_in[3];
  float* out = (float*)d_out;
  char* ws = (char*)d_ws;
  unsigned* bm = (unsigned*)(ws + OFF_BM);
  float* y = (float*)(ws + OFF_Y);
  float* z = (float*)(ws + OFF_Z);

  hipMemsetAsync(bm, 0, BM_BYTES, stream);   // full 32 MB bitmap
  k1<<<GEMMB + FILLB, 256, 0, stream>>>(x, ei, W, Bm, y, z, bm);
  gather_k<<<NN / RPB, 256, 0, stream>>>(bm, y, z, out);
}

// Round 12
// 69.836 us; speedup vs baseline: 3.2720x; 1.0115x over previous
//
#include <hip/hip_runtime.h>

#define NN  16384
#define NE  524288
#define D   128
#define GEMMB 512
#define FILLB 256

// ws layout (bytes); total 48 MB (ws evidenced ~260 MB)
#define OFF_BM 0u          // uint[16384*512] = 32 MB adjacency bitmap: bit(dst,src)
#define OFF_Y  33554432u   // float[16384*128] = 8 MB   y = x @ W^T
#define OFF_Z  41943040u   // float[16384*128] = 8 MB   z = x @ B^T

typedef __bf16 bf16x4 __attribute__((ext_vector_type(4)));
typedef __bf16 bf16x8 __attribute__((ext_vector_type(8)));
typedef float  f32x4  __attribute__((ext_vector_type(4)));
typedef unsigned short u16;

// Zero the 32 MB bitmap: 512 blocks x 256 thr x 16 x uint4 (16 B) = 32 MB.
// Replaces rocclr fillBufferAligned, which profiled at only ~800 GB/s (r11).
__global__ __launch_bounds__(256) void zero_bm_k(uint4* __restrict__ bm4) {
  int i = blockIdx.x * 256 + threadIdx.x;        // 0..131071
#pragma unroll
  for (int u = 0; u < 16; ++u)
    bm4[(size_t)u * 131072 + i] = uint4{0, 0, 0, 0};
}

// K1: blocks [0,512): [y|z] = x @ [W|B]^T via bf16 MFMA (K=128, 32 rows/block).
//     blocks [512,768): edge pass -> adjacency bitmap atomicOr (2048 edges/block).
// Data-independent roles fused so MFMA-bound and atomic-bound work co-schedule.
__global__ __launch_bounds__(256, 2) void k1(const float* __restrict__ x,
                                             const int* __restrict__ ei,
                                             const float* __restrict__ W,
                                             const float* __restrict__ Bm,
                                             float* __restrict__ y,
                                             float* __restrict__ z,
                                             unsigned* __restrict__ bm) {
  __shared__ __bf16 sA[32][40];    // 2.5 KB
  __shared__ __bf16 sB[256][40];   // 20 KB  (rows 0..127 = W, 128..255 = B)
  __shared__ int s_any;
  int b = blockIdx.x, t = threadIdx.x;

  if (b < GEMMB) {
    int l = t & 63, wid = t >> 6;
    int g = l >> 4, ln = l & 15;
    int mh = wid & 1, nh = wid >> 1;
    int row0 = b * 32;
    f32x4 acc[8];
#pragma unroll
    for (int nb = 0; nb < 8; ++nb) acc[nb] = f32x4{0.f, 0.f, 0.f, 0.f};

    for (int kc = 0; kc < 4; ++kc) {
      int kb = kc * 32;
      __syncthreads();
      {                                   // A: 32 rows x 32 k from x
        int rr = t >> 3, q = t & 7;
        float4 v = *(const float4*)&x[(size_t)(row0 + rr) * D + kb + q * 4];
        bf16x4 w = {(__bf16)v.x, (__bf16)v.y, (__bf16)v.z, (__bf16)v.w};
        *(bf16x4*)&sA[rr][q * 4] = w;
      }
#pragma unroll
      for (int u = 0; u < 8; ++u) {       // B': 256 rows (W;B) x 32 k
        int f = u * 256 + t;
        int rr = f >> 3, q = f & 7;
        const float* Bp = (rr < 128) ? &W[(size_t)rr * D] : &Bm[(size_t)(rr - 128) * D];
        float4 v = *(const float4*)&Bp[kb + q * 4];
        bf16x4 w = {(__bf16)v.x, (__bf16)v.y, (__bf16)v.z, (__bf16)v.w};
        *(bf16x4*)&sB[rr][q * 4] = w;
      }
      __syncthreads();
      bf16x8 afr = *(const bf16x8*)&sA[mh * 16 + ln][g * 8];
#pragma unroll
      for (int nb = 0; nb < 8; ++nb) {
        bf16x8 bfr = *(const bf16x8*)&sB[nh * 128 + nb * 16 + ln][g * 8];
        acc[nb] = __builtin_amdgcn_mfma_f32_16x16x32_bf16(afr, bfr, acc[nb], 0, 0, 0);
      }
    }
    float* dstm = (nh == 0) ? y : z;   // C/D: col = ln, row = g*4+i [verified r4-r9]
#pragma unroll
    for (int nb = 0; nb < 8; ++nb)
#pragma unroll
      for (int i = 0; i < 4; ++i)
        dstm[(size_t)(row0 + mh * 16 + g * 4 + i) * D + nb * 16 + ln] = acc[nb][i];
  } else {
    // edge pass: per-block width detect (int64 => odd int32 words all zero)
    if (t == 0) s_any = 0;
    __syncthreads();
    int base = (b - GEMMB) * 2048;
    int any = 0;
#pragma unroll
    for (int u = 0; u < 8; ++u) any |= ei[2 * (base + u * 256 + t) + 1];
    if (any) atomicOr(&s_any, 1);
    __syncthreads();
    int is32 = s_any;
#pragma unroll
    for (int u = 0; u < 8; ++u) {
      int i = base + u * 256 + t;
      int s = is32 ? ei[i] : ei[2 * i];
      int d = is32 ? ei[NE + i] : ei[2 * (NE + i)];
      atomicOr(&bm[((size_t)d << 9) + (s >> 5)], 1u << (s & 31));
    }
  }
}

// K2: out[row] = (1/max(deg,1)) * sum_{src: bit set} y[src] + z[row].
// One row per 32-lane group. Neighbor list rebuilt from the bitmap row with a
// deterministic prefix-scan compaction (ascending src order, replay-stable).
#define RPB 8
__global__ __launch_bounds__(256) void gather_k(const unsigned* __restrict__ bm,
                                                const float* __restrict__ y,
                                                const float* __restrict__ z,
                                                float* __restrict__ out) {
  __shared__ u16 s_col[RPB][128];   // 2 KB
  int t = threadIdx.x, lane = t & 31, r = t >> 5;
  int row = blockIdx.x * RPB + r;
  const unsigned* bmr = bm + ((size_t)row << 9);

  int base = 0;
  for (int ch = 0; ch < 16; ++ch) {        // 16 chunks x 32 words = 512 words
    int w = ch * 32 + lane;
    unsigned m = bmr[w];
    int c = __popc(m);
    int inc = c;                            // inclusive scan over 32-lane group
#pragma unroll
    for (int dlt = 1; dlt < 32; dlt <<= 1) {
      int n = __shfl_up(inc, dlt, 32);
      if (lane >= dlt) inc += n;
    }
    int p = base + inc - c;                 // exclusive offset
    while (m) {
      int bpos = __ffs(m) - 1;
      m &= m - 1;
      if (p < 128) s_col[r][p] = (u16)(w * 32 + bpos);
      ++p;
    }
    base += __shfl(inc, 31, 32);            // chunk total
  }
  int deg = base;
  int k = deg > 128 ? 128 : deg;
  float dinv = 1.0f / (float)(deg > 0 ? deg : 1);

  float4 a[8];
#pragma unroll
  for (int u = 0; u < 8; ++u) a[u] = float4{0.f, 0.f, 0.f, 0.f};
  const float* yl = y + lane * 4;
#define FMA4(aa, vv) { aa.x += vv.x; aa.y += vv.y; aa.z += vv.z; aa.w += vv.w; }
  int j = 0;
  for (; j + 8 <= k; j += 8) {
    float4 v[8];
#pragma unroll
    for (int u = 0; u < 8; ++u)
      v[u] = *(const float4*)(yl + (size_t)s_col[r][j + u] * D);
#pragma unroll
    for (int u = 0; u < 8; ++u) FMA4(a[u], v[u])
  }
  for (; j < k; ++j) {
    float4 v0 = *(const float4*)(yl + (size_t)s_col[r][j] * D);
    FMA4(a[0], v0)
  }
#undef FMA4
#pragma unroll
  for (int u = 4; u < 8; ++u) {
    a[u - 4].x += a[u].x; a[u - 4].y += a[u].y;
    a[u - 4].z += a[u].z; a[u - 4].w += a[u].w;
  }
  float4 zv = *(const float4*)(z + (size_t)row * D + lane * 4);
  float4 o;
  o.x = (a[0].x + a[1].x + a[2].x + a[3].x) * dinv + zv.x;
  o.y = (a[0].y + a[1].y + a[2].y + a[3].y) * dinv + zv.y;
  o.z = (a[0].z + a[1].z + a[2].z + a[3].z) * dinv + zv.z;
  o.w = (a[0].w + a[1].w + a[2].w + a[3].w) * dinv + zv.w;
  *(float4*)(out + (size_t)row * D + lane * 4) = o;
}

extern "C" void kernel_launch(void* const* d_in, const int* in_sizes, int n_in,
                              void* d_out, int out_size, void* d_ws, size_t ws_size,
                              hipStream_t stream) {
  const float* x = (const float*)d_in[0];
  const int* ei = (const int*)d_in[1];
  const float* W = (const float*)d_in[2];
  const float* Bm = (const float*)d_in[3];
  float* out = (float*)d_out;
  char* ws = (char*)d_ws;
  unsigned* bm = (unsigned*)(ws + OFF_BM);
  float* y = (float*)(ws + OFF_Y);
  float* z = (float*)(ws + OFF_Z);

  zero_bm_k<<<512, 256, 0, stream>>>((uint4*)bm);
  k1<<<GEMMB + FILLB, 256, 0, stream>>>(x, ei, W, Bm, y, z, bm);
  gather_k<<<NN / RPB, 256, 0, stream>>>(bm, y, z, out);
}